// Round 7
// baseline (216.878 us; speedup 1.0000x reference)
//
#include <hip/hip_runtime.h>
#include <stdint.h>

#define B_IMG  8
#define NANCH  17328          // A*HW = 3*5776
#define NCLS   80
#define TOPK   200
#define NTHR   256
#define CHUNK  64             // anchors per scatter block
#define NBLK_N ((NANCH + CHUNK - 1) / CHUNK)   // 271
#define CAND_CAP 2560         // per-(b,c) candidate buffer (E=1733, 21 sigma)
#define THRESH_HI 0.9f

// ---------------------------------------------------------------------------
// helpers (proven in rounds 1-6)
// ---------------------------------------------------------------------------
__device__ __forceinline__ void hist_add(float s, unsigned int* hist) {
  if (s > 0.5f) {
    unsigned int bin = (__float_as_uint(s) - 0x3F000000u) >> 15;
    if (bin > 255u) bin = 255u;
    atomicAdd(&hist[bin], 1u);
  }
}

// ---------------------------------------------------------------------------
// K0: zero the per-(b,c) candidate counters (ws not re-poisoned between runs)
// ---------------------------------------------------------------------------
__global__ void init_k(unsigned int* __restrict__ cnt) {
  int i = blockIdx.x * 256 + threadIdx.x;
  if (i < B_IMG * NCLS) cnt[i] = 0u;
}

// ---------------------------------------------------------------------------
// K1 (scatter v2): 64-anchor x 80-class tile in LDS; each wave owns 20
// classes; ONE ballot per class -> one global atomic -> direct global writes.
// No shared-counter serialization. Overflow -> cnt > CAP -> stage1 fallback.
// ---------------------------------------------------------------------------
__global__ __launch_bounds__(NTHR) void scatter_k(
    const float* __restrict__ scores,
    unsigned int* __restrict__ cnt,           // [B*NCLS]
    unsigned long long* __restrict__ cand) {  // [B*NCLS][CAND_CAP]
  const int nb = blockIdx.x;                  // 0..NBLK_N-1
  const int b  = blockIdx.y;
  const int tid = threadIdx.x;
  const int wv = tid >> 6, lane = tid & 63;
  const int n0 = nb * CHUNK;

  __shared__ float tile[CHUNK][81];           // pad 81: conflict-free col reads

  const int nrow = (NANCH - n0 < CHUNK) ? (NANCH - n0) : CHUNK;
  const int nf4 = nrow * (NCLS / 4);
  const float4* src4 = (const float4*)(scores + (size_t)(b * NANCH + n0) * NCLS);
  for (int f = tid; f < nf4; f += NTHR) {
    float4 v = src4[f];                       // fully coalesced (row-major flat)
    int n = f / 20, c4 = (f - n * 20) * 4;
    tile[n][c4] = v.x; tile[n][c4 + 1] = v.y;
    tile[n][c4 + 2] = v.z; tile[n][c4 + 3] = v.w;
  }
  __syncthreads();

  const bool rv = (lane < nrow);
  const unsigned long long lt = (1ull << lane) - 1ull;
  const int cbase = wv * 20;
#pragma unroll 4
  for (int cc = 0; cc < 20; ++cc) {
    const int c = cbase + cc;
    float s = rv ? tile[lane][c] : 0.f;
    const bool cd = (s > THRESH_HI);
    unsigned long long bal = __ballot(cd);
    if (bal) {
      const int bc = b * NCLS + c;
      unsigned int base = 0u;
      if (lane == 0) base = atomicAdd(&cnt[bc], (unsigned int)__popcll(bal));
      base = (unsigned int)__shfl((int)base, 0, 64);
      if (cd) {
        unsigned int pos = base + (unsigned int)__popcll(bal & lt);
        if (pos < CAND_CAP)
          cand[(size_t)bc * CAND_CAP + pos] =
              ((unsigned long long)__float_as_uint(s) << 32) |
              (unsigned long long)(0xFFFFFFFFu - (unsigned int)(n0 + lane));
        // dropped writes leave cnt > CAND_CAP -> fallback path
      }
    }
  }
}

// ---------------------------------------------------------------------------
// K2 (stage1 v2): per-(b,c) exact top-200 from candidate buffer, keys held in
// registers (static indexing). Strided full-scan fallback if count bad.
// Gathers boxes, writes staged (box4, key) records.
// ---------------------------------------------------------------------------
__global__ __launch_bounds__(NTHR) void stage1_k(
    const float* __restrict__ scores, const float* __restrict__ boxes,
    const unsigned int* __restrict__ cnt, const unsigned long long* __restrict__ cand,
    float4* __restrict__ stagedBox, unsigned long long* __restrict__ stagedKey) {
  const int bc = blockIdx.x;
  const int b = bc / NCLS;
  const int c = bc - b * NCLS;
  const int tid = threadIdx.x;

  __shared__ unsigned long long selk[512];
  __shared__ unsigned int hist[256];
  __shared__ unsigned int sh_cutbits;
  __shared__ int sh_m;

  for (int j = tid; j < 256; j += NTHR) hist[j] = 0u;
  if (tid == 0) sh_m = 0;
  __syncthreads();

  const unsigned int m = cnt[bc];

  if (m >= TOPK && m <= CAND_CAP) {
    // ---------------- fast path: registers hold this thread's keys ----------
    const unsigned long long* cb = cand + (size_t)bc * CAND_CAP;
    unsigned long long held[10];
#pragma unroll
    for (int it = 0; it < 10; ++it) {
      unsigned int j = (unsigned int)tid + (unsigned int)it * NTHR;
      held[it] = (j < m) ? cb[j] : 0ull;      // valid keys are never 0
      if (held[it]) {
        unsigned int bin = ((unsigned int)(held[it] >> 32) - 0x3F000000u) >> 15;
        if (bin > 255u) bin = 255u;
        atomicAdd(&hist[bin], 1u);
      }
    }
    __syncthreads();

    // wave-parallel cutoff (proven)
    if (tid < 64) {
      int base = 255 - 4 * tid;
      int s4 = (int)(hist[base] + hist[base - 1] + hist[base - 2] + hist[base - 3]);
      int cum = s4;
      for (int d = 1; d < 64; d <<= 1) {
        int o = __shfl_up(cum, d, 64);
        if (tid >= d) cum += o;
      }
      unsigned long long bal = __ballot(cum >= TOPK);
      if (bal == 0ull) {
        if (tid == 0) sh_cutbits = 0x3F000000u;
      } else {
        int l0 = __builtin_ctzll(bal);
        if (tid == l0) {
          unsigned int acc = (unsigned int)(cum - s4);
          int cutbin = base - 3;
          for (int k = 0; k < 4; ++k) {
            acc += hist[base - k];
            if (acc >= TOPK) { cutbin = base - k; break; }
          }
          sh_cutbits = 0x3F000000u + ((unsigned int)cutbin << 15);
        }
      }
    }
    __syncthreads();
    const unsigned int cutbits = sh_cutbits;

#pragma unroll
    for (int it = 0; it < 10; ++it) {
      if (held[it] && (unsigned int)(held[it] >> 32) >= cutbits) {
        int slot = atomicAdd(&sh_m, 1);
        if (slot < 512) selk[slot] = held[it];
      }
    }
    __syncthreads();
  } else {
    // ---------------- fallback: strided 2-pass (proven rd1 code) ------------
    const float* src = scores + (size_t)b * NANCH * NCLS + c;
    for (int i = tid; i < NANCH; i += NTHR) hist_add(src[(size_t)i * NCLS], hist);
    __syncthreads();

    if (tid == 0) {
      unsigned int acc = 0;
      int cut = 0;
      for (int bin = 255; bin >= 0; --bin) {
        acc += hist[bin];
        if (acc >= TOPK) { cut = bin; break; }
      }
      sh_cutbits = 0x3F000000u + ((unsigned int)cut << 15);
    }
    __syncthreads();
    const unsigned int cutbits = sh_cutbits;

    for (int i = tid; i < NANCH; i += NTHR) {
      float s = src[(size_t)i * NCLS];
      if (s > 0.5f && __float_as_uint(s) >= cutbits) {
        int slot = atomicAdd(&sh_m, 1);
        if (slot < 512)
          selk[slot] = ((unsigned long long)__float_as_uint(s) << 32) |
                       (unsigned long long)(0xFFFFFFFFu - (unsigned int)i);
      }
    }
    __syncthreads();
  }

  int M = sh_m; if (M > 512) M = 512;
  const int S = (M <= 256) ? 256 : 512;
  for (int j = M + tid; j < S; j += NTHR) selk[j] = 0ull;

  // ---- bitonic sort S elements, descending (proven) ----
  for (int size = 2; size <= S; size <<= 1) {
    for (int st = size >> 1; st > 0; st >>= 1) {
      __syncthreads();
      for (int t = tid; t < (S >> 1); t += NTHR) {
        int lo = 2 * t - (t & (st - 1));
        int hi = lo + st;
        bool desc = ((lo & size) == 0);
        unsigned long long a = selk[lo], bb = selk[hi];
        if ((a < bb) == desc) { selk[lo] = bb; selk[hi] = a; }
      }
    }
  }
  __syncthreads();

  // ---- gather boxes + write staged records ----
  {
    unsigned long long key = selk[tid];
    int valid = (tid < TOPK) && (key != 0ull);
    unsigned int idx = 0xFFFFFFFFu - (unsigned int)(key & 0xFFFFFFFFull);
    float4 bx = make_float4(0.f, 0.f, 0.f, 0.f);
    if (valid) bx = ((const float4*)boxes)[(size_t)b * NANCH + idx];
    stagedBox[(size_t)bc * 256 + tid] = bx;
    stagedKey[(size_t)bc * 256 + tid] = key;
  }
}

// ---------------------------------------------------------------------------
// K3: suppression-matrix build -> global sup words. 4 blocks per (b,c),
// rows i = 16k + 4*wv + h. Guard-band IEEE div is branch-skipped.
// ---------------------------------------------------------------------------
__global__ __launch_bounds__(NTHR) void supbuild_k(
    const float4* __restrict__ stagedBox,
    unsigned long long* __restrict__ supg) {   // [B*NCLS][TOPK][4]
  const int blk = blockIdx.x;
  const int h = blk & 3;
  const int bc = blk >> 2;
  const int tid = threadIdx.x;
  const int wv = tid >> 6, lane = tid & 63;

  __shared__ float sx1[256], sy1[256], sx2[256], sy2[256], sar[256];

  if (tid < 256) {
    float4 bx = stagedBox[(size_t)bc * 256 + tid];
    sx1[tid] = bx.x; sy1[tid] = bx.y; sx2[tid] = bx.z; sy2[tid] = bx.w;
    sar[tid] = __fmul_rn(bx.z - bx.x, bx.w - bx.y);   // _rn: block FMA contraction
  }
  __syncthreads();

  float jx1[4], jy1[4], jx2[4], jy2[4], ja[4];
#pragma unroll
  for (int r = 0; r < 4; ++r) {
    int j = (r << 6) | lane;
    jx1[r] = sx1[j]; jy1[r] = sy1[j]; jx2[r] = sx2[j]; jy2[r] = sy2[j];
    ja[r] = sar[j];
  }

  for (int k = 0; k < 13; ++k) {
    const int i = 16 * k + 4 * wv + h;       // block quartet covers 0..207
    if (i >= TOPK) break;                    // wave-uniform
    const float xi1 = sx1[i], yi1 = sy1[i], xi2 = sx2[i], yi2 = sy2[i];
    const float ai = sar[i];
    unsigned long long w[4];
#pragma unroll
    for (int r = 0; r < 4; ++r) {
      unsigned long long word = 0ull;
      if ((r << 6) + 63 > i) {               // wave-uniform
        const int j = (r << 6) | lane;
        const bool vp = (j > i) && (j < TOPK);
        float xx1 = fmaxf(xi1, jx1[r]);
        float yy1 = fmaxf(yi1, jy1[r]);
        float xx2 = fminf(xi2, jx2[r]);
        float yy2 = fminf(yi2, jy2[r]);
        float iw = fmaxf(0.f, __fsub_rn(xx2, xx1));
        float ih = fmaxf(0.f, __fsub_rn(yy2, yy1));
        float inter = __fmul_rn(iw, ih);
        float denom = __fsub_rn(__fadd_rn(ai, ja[r]), inter);
        float q = __fmul_rn(inter, __builtin_amdgcn_rcpf(denom));
        bool s = vp && (q > 0.5f);
        bool gbad = vp && (fabsf(q - 0.5f) < 1e-5f);
        if (__ballot(gbad)) {                // ~never: exact IEEE div, XLA-bitwise
          if (gbad) s = __fdiv_rn(inter, denom) > 0.5f;
        }
        word = __ballot(s);
      }
      w[r] = word;
    }
    if (lane == 0) {
      ulonglong2* dst = (ulonglong2*)(supg + ((size_t)bc * TOPK + i) * 4);
      ulonglong2 t0; t0.x = w[0]; t0.y = w[1];
      ulonglong2 t1; t1.x = w[2]; t1.y = w[3];
      dst[0] = t0; dst[1] = t1;
    }
  }
}

// ---------------------------------------------------------------------------
// K4: serial bit-scan (wave 0) + emit via LDS-staged float4 stores (proven)
// ---------------------------------------------------------------------------
__global__ __launch_bounds__(NTHR) void scanemit_k(
    const float4* __restrict__ stagedBox, const unsigned long long* __restrict__ stagedKey,
    const unsigned long long* __restrict__ supg, float* __restrict__ out) {
  const int bc = blockIdx.x;
  const int c = bc - (bc / NCLS) * NCLS;
  const int tid = threadIdx.x;

  __shared__ float sx1[256], sy1[256], sx2[256], sy2[256], ssc[256];
  __shared__ int skeep[256];
  __shared__ __align__(16) unsigned long long sup[TOPK][4];   // 6.4 KB
  __shared__ __align__(16) float eout[TOPK * 6];

  {
    unsigned long long key = stagedKey[(size_t)bc * 256 + tid];
    float4 bx = stagedBox[(size_t)bc * 256 + tid];
    int valid = (tid < TOPK) && (key != 0ull);
    sx1[tid] = bx.x; sy1[tid] = bx.y; sx2[tid] = bx.z; sy2[tid] = bx.w;
    ssc[tid] = valid ? __uint_as_float((unsigned int)(key >> 32)) : 0.f;
    skeep[tid] = valid;
  }
  {
    const ulonglong2* src = (const ulonglong2*)(supg + (size_t)bc * TOPK * 4);
    ulonglong2* dst = (ulonglong2*)&sup[0][0];
    for (int f = tid; f < TOPK * 2; f += NTHR) dst[f] = src[f];
  }
  __syncthreads();

  if (tid < 64) {
    unsigned long long k0 = __ballot(skeep[tid] != 0);
    unsigned long long k1 = __ballot(skeep[64 + tid] != 0);
    unsigned long long k2 = __ballot(skeep[128 + tid] != 0);
    unsigned long long k3 = __ballot(skeep[192 + tid] != 0);  // 200..255 are 0
#define NMS_SCAN_WORD(KW, BASE, CNT)                                     \
    _Pragma("unroll 8")                                                  \
    for (int li = 0; li < (CNT); ++li) {                                 \
      const ulonglong2* s2p =                                            \
          reinterpret_cast<const ulonglong2*>(&sup[(BASE) + li][0]);     \
      ulonglong2 sa = s2p[0];                                            \
      ulonglong2 sb = s2p[1];                                            \
      unsigned long long m = 0ull - ((KW >> li) & 1ull);                 \
      k0 &= ~(sa.x & m); k1 &= ~(sa.y & m);                              \
      k2 &= ~(sb.x & m); k3 &= ~(sb.y & m);                              \
    }
    NMS_SCAN_WORD(k0, 0, 64)
    NMS_SCAN_WORD(k1, 64, 64)
    NMS_SCAN_WORD(k2, 128, 64)
    NMS_SCAN_WORD(k3, 192, 8)
#undef NMS_SCAN_WORD
    skeep[tid]        = (int)((k0 >> tid) & 1ull);
    skeep[64 + tid]   = (int)((k1 >> tid) & 1ull);
    skeep[128 + tid]  = (int)((k2 >> tid) & 1ull);
    skeep[192 + tid]  = (int)((k3 >> tid) & 1ull);
  }
  __syncthreads();

  if (tid < TOPK) {
    int kp = skeep[tid];
    eout[tid * 6 + 0] = kp ? sx1[tid] : 0.f;
    eout[tid * 6 + 1] = kp ? sy1[tid] : 0.f;
    eout[tid * 6 + 2] = kp ? sx2[tid] : 0.f;
    eout[tid * 6 + 3] = kp ? sy2[tid] : 0.f;
    eout[tid * 6 + 4] = kp ? ssc[tid] : 0.f;
    eout[tid * 6 + 5] = kp ? (float)c : 0.f;
  }
  __syncthreads();

  float4* out4 = (float4*)(out + (size_t)bc * (TOPK * 6));
  const float4* e4 = (const float4*)eout;
  for (int f = tid; f < (TOPK * 6) / 4; f += NTHR) out4[f] = e4[f];
}

// ---------------------------------------------------------------------------
// Fallback: proven monolithic kernel (strided reads), used only if ws tiny
// ---------------------------------------------------------------------------
__global__ __launch_bounds__(NTHR) void select_nms_k(
    const float* __restrict__ boxes, const float* __restrict__ scores,
    float* __restrict__ out) {
  const int blk = blockIdx.x;
  const int b = blk / NCLS;
  const int c = blk - b * NCLS;
  const int tid = threadIdx.x;

  __shared__ unsigned int hist[256];
  __shared__ unsigned long long keys[1024];
  __shared__ float sx1[TOPK], sy1[TOPK], sx2[TOPK], sy2[TOPK], sar[TOPK], ssc[TOPK];
  __shared__ int skeep[TOPK];
  __shared__ unsigned int sh_cutbits;
  __shared__ int sh_m;

  const float* src = scores + (size_t)b * NANCH * NCLS + c;

  for (int j = tid; j < 256; j += NTHR) hist[j] = 0;
  if (tid == 0) sh_m = 0;
  __syncthreads();

  for (int i = tid; i < NANCH; i += NTHR) hist_add(src[(size_t)i * NCLS], hist);
  __syncthreads();

  if (tid == 0) {
    unsigned int acc = 0;
    int cut = 0;
    for (int bin = 255; bin >= 0; --bin) {
      acc += hist[bin];
      if (acc >= TOPK) { cut = bin; break; }
    }
    sh_cutbits = 0x3F000000u + ((unsigned int)cut << 15);
  }
  __syncthreads();
  const unsigned int cutbits = sh_cutbits;

  for (int i = tid; i < NANCH; i += NTHR) {
    float s = src[(size_t)i * NCLS];
    if (s > 0.5f && __float_as_uint(s) >= cutbits) {
      int slot = atomicAdd(&sh_m, 1);
      if (slot < 1024)
        keys[slot] = ((unsigned long long)__float_as_uint(s) << 32) |
                     (unsigned long long)(0xFFFFFFFFu - (unsigned int)i);
    }
  }
  __syncthreads();
  int M = sh_m; if (M > 1024) M = 1024;
  for (int j = M + tid; j < 1024; j += NTHR) keys[j] = 0ull;

  for (int size = 2; size <= 1024; size <<= 1) {
    for (int st = size >> 1; st > 0; st >>= 1) {
      __syncthreads();
      for (int t = tid; t < 512; t += NTHR) {
        int lo = 2 * t - (t & (st - 1));
        int hi = lo + st;
        bool desc = ((lo & size) == 0);
        unsigned long long a = keys[lo], bb = keys[hi];
        if ((a < bb) == desc) { keys[lo] = bb; keys[hi] = a; }
      }
    }
  }
  __syncthreads();

  if (tid < TOPK) {
    unsigned long long key = keys[tid];
    int valid = (key != 0ull);
    float sc = __uint_as_float((unsigned int)(key >> 32));
    unsigned int idx = 0xFFFFFFFFu - (unsigned int)(key & 0xFFFFFFFFull);
    float4 bx = make_float4(0.f, 0.f, 0.f, 0.f);
    if (valid) bx = ((const float4*)boxes)[(size_t)b * NANCH + idx];
    sx1[tid] = bx.x; sy1[tid] = bx.y; sx2[tid] = bx.z; sy2[tid] = bx.w;
    sar[tid] = __fmul_rn(bx.z - bx.x, bx.w - bx.y);
    ssc[tid] = valid ? sc : 0.f;
    skeep[tid] = valid;
  }
  __syncthreads();

  if (tid < 64) {
    const int lane = tid;
    float x1v[4], y1v[4], x2v[4], y2v[4], av[4];
    int km = 0;
#pragma unroll
    for (int r = 0; r < 4; ++r) {
      int j = lane + (r << 6);
      if (j < TOPK) {
        x1v[r] = sx1[j]; y1v[r] = sy1[j]; x2v[r] = sx2[j]; y2v[r] = sy2[j];
        av[r] = sar[j];
        if (skeep[j]) km |= (1 << r);
      } else {
        x1v[r] = 0.f; y1v[r] = 0.f; x2v[r] = 0.f; y2v[r] = 0.f; av[r] = 0.f;
      }
    }
#pragma unroll
    for (int ri = 0; ri < 4; ++ri) {
      const int imax = (ri == 3) ? (TOPK - 192) : 64;
      for (int li = 0; li < imax; ++li) {
        const int i = (ri << 6) + li;
        int kmi = __shfl(km, li, 64);
        if (!((kmi >> ri) & 1)) continue;
        float xi1 = __shfl(x1v[ri], li, 64);
        float yi1 = __shfl(y1v[ri], li, 64);
        float xi2 = __shfl(x2v[ri], li, 64);
        float yi2 = __shfl(y2v[ri], li, 64);
        float ai  = __shfl(av[ri],  li, 64);
#pragma unroll
        for (int r = 0; r < 4; ++r) {
          int j = lane + (r << 6);
          if (j > i && j < TOPK && ((km >> r) & 1)) {
            float xx1 = fmaxf(xi1, x1v[r]);
            float yy1 = fmaxf(yi1, y1v[r]);
            float xx2 = fminf(xi2, x2v[r]);
            float yy2 = fminf(yi2, y2v[r]);
            float iw = fmaxf(0.f, __fsub_rn(xx2, xx1));
            float ih = fmaxf(0.f, __fsub_rn(yy2, yy1));
            float inter = __fmul_rn(iw, ih);
            float denom = __fsub_rn(__fadd_rn(ai, av[r]), inter);
            float iou = __fdiv_rn(inter, denom);
            if (iou > 0.5f) km &= ~(1 << r);
          }
        }
      }
    }
#pragma unroll
    for (int r = 0; r < 4; ++r) {
      int j = lane + (r << 6);
      if (j < TOPK) skeep[j] = (km >> r) & 1;
    }
  }
  __syncthreads();

  const size_t base = ((size_t)b * NCLS + c) * (TOPK * 6);
  for (int f = tid; f < TOPK * 6; f += NTHR) {
    int k = f / 6, comp = f - k * 6;
    float v = 0.f;
    if (skeep[k]) {
      switch (comp) {
        case 0: v = sx1[k]; break;
        case 1: v = sy1[k]; break;
        case 2: v = sx2[k]; break;
        case 3: v = sy2[k]; break;
        case 4: v = ssc[k]; break;
        default: v = (float)c; break;
      }
    }
    out[base + f] = v;
  }
}

// ---------------------------------------------------------------------------
extern "C" void kernel_launch(void* const* d_in, const int* in_sizes, int n_in,
                              void* d_out, int out_size, void* d_ws, size_t ws_size,
                              hipStream_t stream) {
  (void)in_sizes; (void)n_in; (void)out_size;
  const float* boxes  = (const float*)d_in[0];
  const float* scores = (const float*)d_in[1];
  float* out = (float*)d_out;

  const int NBC = B_IMG * NCLS;                                   // 640
  const size_t need_cnt = 4096;                                   // 640*4 rounded
  const size_t need_cd  = (size_t)NBC * CAND_CAP * sizeof(uint64_t);   // 13.1 MB
  const size_t need_sb  = (size_t)NBC * 256 * sizeof(float4);          // 2.6 MB
  const size_t need_sk  = (size_t)NBC * 256 * sizeof(uint64_t);        // 1.3 MB
  const size_t need_sp  = (size_t)NBC * TOPK * 4 * sizeof(uint64_t);   // 4.1 MB
  const size_t need = need_cnt + need_cd + need_sb + need_sk + need_sp; // ~21 MB

  if (ws_size >= need) {
    char* w = (char*)d_ws;
    unsigned int* cnt             = (unsigned int*)w;          w += need_cnt;
    unsigned long long* cand      = (unsigned long long*)w;    w += need_cd;
    float4* stagedBox             = (float4*)w;                w += need_sb;
    unsigned long long* stagedKey = (unsigned long long*)w;    w += need_sk;
    unsigned long long* supg      = (unsigned long long*)w;

    init_k<<<(NBC + 255) / 256, 256, 0, stream>>>(cnt);
    scatter_k<<<dim3(NBLK_N, B_IMG), NTHR, 0, stream>>>(scores, cnt, cand);
    stage1_k<<<NBC, NTHR, 0, stream>>>(scores, boxes, cnt, cand, stagedBox, stagedKey);
    supbuild_k<<<NBC * 4, NTHR, 0, stream>>>(stagedBox, supg);
    scanemit_k<<<NBC, NTHR, 0, stream>>>(stagedBox, stagedKey, supg, out);
  } else {
    select_nms_k<<<NBC, NTHR, 0, stream>>>(boxes, scores, out);
  }
}

// Round 8
// 77.753 us; speedup vs baseline: 2.7893x; 2.7893x over previous
//
#include <hip/hip_runtime.h>
#include <stdint.h>

#define B_IMG  8
#define NANCH  17328          // A*HW = 3*5776
#define NCLS   80
#define TOPK   200
#define NTHR   256
#define CHUNK  64             // anchors per scatter block
#define NCHK   ((NANCH + CHUNK - 1) / CHUNK)   // 271
#define NCHKP  272            // padded
#define SLOT   24             // per-(bc,chunk) candidate slots; P(Bin(64,.1)>=24)~8e-8
#define ALLK_CAP 2608         // stage1 LDS candidate cap (mean 1733, 22 sigma)
#define THRESH_HI 0.9f

// ---------------------------------------------------------------------------
// helpers (proven in rounds 1-7)
// ---------------------------------------------------------------------------
__device__ __forceinline__ void hist_add(float s, unsigned int* hist) {
  if (s > 0.5f) {
    unsigned int bin = (__float_as_uint(s) - 0x3F000000u) >> 15;
    if (bin > 255u) bin = 255u;
    atomicAdd(&hist[bin], 1u);
  }
}

// ---------------------------------------------------------------------------
// K1 (scatter v3): ATOMIC-FREE. 64-anchor x 80-class tile in LDS; per class
// one ballot; candidates write to deterministic slots cand[bc][chunk][rank];
// lane0 stores the raw count (u8, unconditional -> no init kernel).
// count > SLOT (dropped writes) poisons that bc -> stage1 exact fallback.
// ---------------------------------------------------------------------------
__global__ __launch_bounds__(NTHR) void scatter_k(
    const float* __restrict__ scores,
    unsigned char* __restrict__ cnt2,         // [B*NCLS][NCHKP]
    unsigned long long* __restrict__ cand) {  // [B*NCLS][NCHK][SLOT]
  const int nb = blockIdx.x;                  // chunk id 0..NCHK-1
  const int b  = blockIdx.y;
  const int tid = threadIdx.x;
  const int wv = tid >> 6, lane = tid & 63;
  const int n0 = nb * CHUNK;

  __shared__ float tile[CHUNK][81];           // pad 81: conflict-free col reads

  const int nrow = (NANCH - n0 < CHUNK) ? (NANCH - n0) : CHUNK;
  const int nf4 = nrow * (NCLS / 4);
  const float4* src4 = (const float4*)(scores + (size_t)(b * NANCH + n0) * NCLS);
  for (int f = tid; f < nf4; f += NTHR) {
    float4 v = src4[f];                       // fully coalesced (row-major flat)
    int n = f / 20, c4 = (f - n * 20) * 4;
    tile[n][c4] = v.x; tile[n][c4 + 1] = v.y;
    tile[n][c4 + 2] = v.z; tile[n][c4 + 3] = v.w;
  }
  __syncthreads();

  const bool rv = (lane < nrow);
  const unsigned long long lt = (1ull << lane) - 1ull;
  const int cbase = wv * 20;
#pragma unroll 4
  for (int cc = 0; cc < 20; ++cc) {
    const int c = cbase + cc;
    const int bc = b * NCLS + c;
    float s = rv ? tile[lane][c] : 0.f;
    const bool cd = (s > THRESH_HI);
    unsigned long long bal = __ballot(cd);
    if (cd) {
      unsigned int r = (unsigned int)__popcll(bal & lt);
      if (r < SLOT)                           // beyond-SLOT dropped: count poisons
        cand[((size_t)bc * NCHK + nb) * SLOT + r] =
            ((unsigned long long)__float_as_uint(s) << 32) |
            (unsigned long long)(0xFFFFFFFFu - (unsigned int)(n0 + lane));
    }
    if (lane == 0)
      cnt2[(size_t)bc * NCHKP + nb] = (unsigned char)__popcll(bal);
  }
}

// ---------------------------------------------------------------------------
// K2 (stage1 v3): per-(b,c) exact top-200 from chunked candidate lists.
// Thread t owns chunks t, t+256: compact to LDS (one LDS atomic per chunk),
// hist on the fly; proven cutoff/select/sort/gather. Fallback if poisoned.
// ---------------------------------------------------------------------------
__global__ __launch_bounds__(NTHR) void stage1_k(
    const float* __restrict__ scores, const float* __restrict__ boxes,
    const unsigned char* __restrict__ cnt2, const unsigned long long* __restrict__ cand,
    float4* __restrict__ stagedBox, unsigned long long* __restrict__ stagedKey) {
  const int bc = blockIdx.x;
  const int b = bc / NCLS;
  const int c = bc - b * NCLS;
  const int tid = threadIdx.x;

  __shared__ unsigned long long allk[ALLK_CAP];   // 20.9 KB
  __shared__ unsigned long long selk[512];
  __shared__ unsigned int hist[256];
  __shared__ unsigned int sh_cutbits;
  __shared__ int sh_m, sh_sel, sh_bad;

  for (int j = tid; j < 256; j += NTHR) hist[j] = 0u;
  if (tid == 0) { sh_m = 0; sh_sel = 0; sh_bad = 0; }
  __syncthreads();

  // ---- compact candidate chunks to LDS + histogram ------------------------
  for (int ch = tid; ch < NCHK; ch += NTHR) {
    unsigned int ci = (unsigned int)cnt2[(size_t)bc * NCHKP + ch];
    if (ci > SLOT) { sh_bad = 1; continue; }         // overflowed chunk
    if (ci == 0u) continue;
    int base = atomicAdd(&sh_m, (int)ci);
    if (base + (int)ci > ALLK_CAP) { sh_bad = 1; continue; }
    const unsigned long long* cb = cand + ((size_t)bc * NCHK + ch) * SLOT;
    for (unsigned int j = 0; j < ci; ++j) {
      unsigned long long k = cb[j];
      allk[base + j] = k;
      unsigned int bin = ((unsigned int)(k >> 32) - 0x3F000000u) >> 15;
      if (bin > 255u) bin = 255u;
      atomicAdd(&hist[bin], 1u);
    }
  }
  __syncthreads();

  const int Mall = sh_m;
  const bool fast = (!sh_bad) && (Mall >= TOPK);

  if (fast) {
    // ---- wave-parallel cutoff (proven) ----
    if (tid < 64) {
      int base = 255 - 4 * tid;
      int s4 = (int)(hist[base] + hist[base - 1] + hist[base - 2] + hist[base - 3]);
      int cum = s4;
      for (int d = 1; d < 64; d <<= 1) {
        int o = __shfl_up(cum, d, 64);
        if (tid >= d) cum += o;
      }
      unsigned long long bal = __ballot(cum >= TOPK);
      if (bal == 0ull) {
        if (tid == 0) sh_cutbits = 0x3F000000u;
      } else {
        int l0 = __builtin_ctzll(bal);
        if (tid == l0) {
          unsigned int acc = (unsigned int)(cum - s4);
          int cutbin = base - 3;
          for (int k = 0; k < 4; ++k) {
            acc += hist[base - k];
            if (acc >= TOPK) { cutbin = base - k; break; }
          }
          sh_cutbits = 0x3F000000u + ((unsigned int)cutbin << 15);
        }
      }
    }
    __syncthreads();
    const unsigned int cutbits = sh_cutbits;

    for (int j = tid; j < Mall; j += NTHR) {
      unsigned long long k = allk[j];
      if ((unsigned int)(k >> 32) >= cutbits) {
        int slot = atomicAdd(&sh_sel, 1);
        if (slot < 512) selk[slot] = k;
      }
    }
    __syncthreads();
  } else {
    // ---- fallback: strided 2-pass full scan (proven rd1 code) -------------
    for (int j = tid; j < 256; j += NTHR) hist[j] = 0u;
    __syncthreads();
    const float* src = scores + (size_t)b * NANCH * NCLS + c;
    for (int i = tid; i < NANCH; i += NTHR) hist_add(src[(size_t)i * NCLS], hist);
    __syncthreads();

    if (tid == 0) {
      unsigned int acc = 0;
      int cut = 0;
      for (int bin = 255; bin >= 0; --bin) {
        acc += hist[bin];
        if (acc >= TOPK) { cut = bin; break; }
      }
      sh_cutbits = 0x3F000000u + ((unsigned int)cut << 15);
    }
    __syncthreads();
    const unsigned int cutbits = sh_cutbits;

    for (int i = tid; i < NANCH; i += NTHR) {
      float s = src[(size_t)i * NCLS];
      if (s > 0.5f && __float_as_uint(s) >= cutbits) {
        int slot = atomicAdd(&sh_sel, 1);
        if (slot < 512)
          selk[slot] = ((unsigned long long)__float_as_uint(s) << 32) |
                       (unsigned long long)(0xFFFFFFFFu - (unsigned int)i);
      }
    }
    __syncthreads();
  }

  int M = sh_sel; if (M > 512) M = 512;
  const int S = (M <= 256) ? 256 : 512;
  for (int j = M + tid; j < S; j += NTHR) selk[j] = 0ull;

  // ---- bitonic sort S elements, descending (proven) ----
  for (int size = 2; size <= S; size <<= 1) {
    for (int st = size >> 1; st > 0; st >>= 1) {
      __syncthreads();
      for (int t = tid; t < (S >> 1); t += NTHR) {
        int lo = 2 * t - (t & (st - 1));
        int hi = lo + st;
        bool desc = ((lo & size) == 0);
        unsigned long long a = selk[lo], bb = selk[hi];
        if ((a < bb) == desc) { selk[lo] = bb; selk[hi] = a; }
      }
    }
  }
  __syncthreads();

  // ---- gather boxes + write staged records (proven) ----
  {
    unsigned long long key = selk[tid];
    int valid = (tid < TOPK) && (key != 0ull);
    unsigned int idx = 0xFFFFFFFFu - (unsigned int)(key & 0xFFFFFFFFull);
    float4 bx = make_float4(0.f, 0.f, 0.f, 0.f);
    if (valid) bx = ((const float4*)boxes)[(size_t)b * NANCH + idx];
    stagedBox[(size_t)bc * 256 + tid] = bx;
    stagedKey[(size_t)bc * 256 + tid] = key;
  }
}

// ---------------------------------------------------------------------------
// K3: suppression-matrix build -> global sup words. 4 blocks per (b,c),
// rows i = 16k + 4*wv + h. Guard-band IEEE div is branch-skipped. (proven)
// ---------------------------------------------------------------------------
__global__ __launch_bounds__(NTHR) void supbuild_k(
    const float4* __restrict__ stagedBox,
    unsigned long long* __restrict__ supg) {   // [B*NCLS][TOPK][4]
  const int blk = blockIdx.x;
  const int h = blk & 3;
  const int bc = blk >> 2;
  const int tid = threadIdx.x;
  const int wv = tid >> 6, lane = tid & 63;

  __shared__ float sx1[256], sy1[256], sx2[256], sy2[256], sar[256];

  if (tid < 256) {
    float4 bx = stagedBox[(size_t)bc * 256 + tid];
    sx1[tid] = bx.x; sy1[tid] = bx.y; sx2[tid] = bx.z; sy2[tid] = bx.w;
    sar[tid] = __fmul_rn(bx.z - bx.x, bx.w - bx.y);   // _rn: block FMA contraction
  }
  __syncthreads();

  float jx1[4], jy1[4], jx2[4], jy2[4], ja[4];
#pragma unroll
  for (int r = 0; r < 4; ++r) {
    int j = (r << 6) | lane;
    jx1[r] = sx1[j]; jy1[r] = sy1[j]; jx2[r] = sx2[j]; jy2[r] = sy2[j];
    ja[r] = sar[j];
  }

  for (int k = 0; k < 13; ++k) {
    const int i = 16 * k + 4 * wv + h;       // block quartet covers 0..207
    if (i >= TOPK) break;                    // wave-uniform
    const float xi1 = sx1[i], yi1 = sy1[i], xi2 = sx2[i], yi2 = sy2[i];
    const float ai = sar[i];
    unsigned long long w[4];
#pragma unroll
    for (int r = 0; r < 4; ++r) {
      unsigned long long word = 0ull;
      if ((r << 6) + 63 > i) {               // wave-uniform
        const int j = (r << 6) | lane;
        const bool vp = (j > i) && (j < TOPK);
        float xx1 = fmaxf(xi1, jx1[r]);
        float yy1 = fmaxf(yi1, jy1[r]);
        float xx2 = fminf(xi2, jx2[r]);
        float yy2 = fminf(yi2, jy2[r]);
        float iw = fmaxf(0.f, __fsub_rn(xx2, xx1));
        float ih = fmaxf(0.f, __fsub_rn(yy2, yy1));
        float inter = __fmul_rn(iw, ih);
        float denom = __fsub_rn(__fadd_rn(ai, ja[r]), inter);
        float q = __fmul_rn(inter, __builtin_amdgcn_rcpf(denom));
        bool s = vp && (q > 0.5f);
        bool gbad = vp && (fabsf(q - 0.5f) < 1e-5f);
        if (__ballot(gbad)) {                // ~never: exact IEEE div, XLA-bitwise
          if (gbad) s = __fdiv_rn(inter, denom) > 0.5f;
        }
        word = __ballot(s);
      }
      w[r] = word;
    }
    if (lane == 0) {
      ulonglong2* dst = (ulonglong2*)(supg + ((size_t)bc * TOPK + i) * 4);
      ulonglong2 t0; t0.x = w[0]; t0.y = w[1];
      ulonglong2 t1; t1.x = w[2]; t1.y = w[3];
      dst[0] = t0; dst[1] = t1;
    }
  }
}

// ---------------------------------------------------------------------------
// K4: serial bit-scan (wave 0) + emit via LDS-staged float4 stores (proven)
// ---------------------------------------------------------------------------
__global__ __launch_bounds__(NTHR) void scanemit_k(
    const float4* __restrict__ stagedBox, const unsigned long long* __restrict__ stagedKey,
    const unsigned long long* __restrict__ supg, float* __restrict__ out) {
  const int bc = blockIdx.x;
  const int c = bc - (bc / NCLS) * NCLS;
  const int tid = threadIdx.x;

  __shared__ float sx1[256], sy1[256], sx2[256], sy2[256], ssc[256];
  __shared__ int skeep[256];
  __shared__ __align__(16) unsigned long long sup[TOPK][4];   // 6.4 KB
  __shared__ __align__(16) float eout[TOPK * 6];

  {
    unsigned long long key = stagedKey[(size_t)bc * 256 + tid];
    float4 bx = stagedBox[(size_t)bc * 256 + tid];
    int valid = (tid < TOPK) && (key != 0ull);
    sx1[tid] = bx.x; sy1[tid] = bx.y; sx2[tid] = bx.z; sy2[tid] = bx.w;
    ssc[tid] = valid ? __uint_as_float((unsigned int)(key >> 32)) : 0.f;
    skeep[tid] = valid;
  }
  {
    const ulonglong2* src = (const ulonglong2*)(supg + (size_t)bc * TOPK * 4);
    ulonglong2* dst = (ulonglong2*)&sup[0][0];
    for (int f = tid; f < TOPK * 2; f += NTHR) dst[f] = src[f];
  }
  __syncthreads();

  if (tid < 64) {
    unsigned long long k0 = __ballot(skeep[tid] != 0);
    unsigned long long k1 = __ballot(skeep[64 + tid] != 0);
    unsigned long long k2 = __ballot(skeep[128 + tid] != 0);
    unsigned long long k3 = __ballot(skeep[192 + tid] != 0);  // 200..255 are 0
#define NMS_SCAN_WORD(KW, BASE, CNT)                                     \
    _Pragma("unroll 8")                                                  \
    for (int li = 0; li < (CNT); ++li) {                                 \
      const ulonglong2* s2p =                                            \
          reinterpret_cast<const ulonglong2*>(&sup[(BASE) + li][0]);     \
      ulonglong2 sa = s2p[0];                                            \
      ulonglong2 sb = s2p[1];                                            \
      unsigned long long m = 0ull - ((KW >> li) & 1ull);                 \
      k0 &= ~(sa.x & m); k1 &= ~(sa.y & m);                              \
      k2 &= ~(sb.x & m); k3 &= ~(sb.y & m);                              \
    }
    NMS_SCAN_WORD(k0, 0, 64)
    NMS_SCAN_WORD(k1, 64, 64)
    NMS_SCAN_WORD(k2, 128, 64)
    NMS_SCAN_WORD(k3, 192, 8)
#undef NMS_SCAN_WORD
    skeep[tid]        = (int)((k0 >> tid) & 1ull);
    skeep[64 + tid]   = (int)((k1 >> tid) & 1ull);
    skeep[128 + tid]  = (int)((k2 >> tid) & 1ull);
    skeep[192 + tid]  = (int)((k3 >> tid) & 1ull);
  }
  __syncthreads();

  if (tid < TOPK) {
    int kp = skeep[tid];
    eout[tid * 6 + 0] = kp ? sx1[tid] : 0.f;
    eout[tid * 6 + 1] = kp ? sy1[tid] : 0.f;
    eout[tid * 6 + 2] = kp ? sx2[tid] : 0.f;
    eout[tid * 6 + 3] = kp ? sy2[tid] : 0.f;
    eout[tid * 6 + 4] = kp ? ssc[tid] : 0.f;
    eout[tid * 6 + 5] = kp ? (float)c : 0.f;
  }
  __syncthreads();

  float4* out4 = (float4*)(out + (size_t)bc * (TOPK * 6));
  const float4* e4 = (const float4*)eout;
  for (int f = tid; f < (TOPK * 6) / 4; f += NTHR) out4[f] = e4[f];
}

// ---------------------------------------------------------------------------
// Fallback: proven monolithic kernel (strided reads), used only if ws tiny
// ---------------------------------------------------------------------------
__global__ __launch_bounds__(NTHR) void select_nms_k(
    const float* __restrict__ boxes, const float* __restrict__ scores,
    float* __restrict__ out) {
  const int blk = blockIdx.x;
  const int b = blk / NCLS;
  const int c = blk - b * NCLS;
  const int tid = threadIdx.x;

  __shared__ unsigned int hist[256];
  __shared__ unsigned long long keys[1024];
  __shared__ float sx1[TOPK], sy1[TOPK], sx2[TOPK], sy2[TOPK], sar[TOPK], ssc[TOPK];
  __shared__ int skeep[TOPK];
  __shared__ unsigned int sh_cutbits;
  __shared__ int sh_m;

  const float* src = scores + (size_t)b * NANCH * NCLS + c;

  for (int j = tid; j < 256; j += NTHR) hist[j] = 0;
  if (tid == 0) sh_m = 0;
  __syncthreads();

  for (int i = tid; i < NANCH; i += NTHR) hist_add(src[(size_t)i * NCLS], hist);
  __syncthreads();

  if (tid == 0) {
    unsigned int acc = 0;
    int cut = 0;
    for (int bin = 255; bin >= 0; --bin) {
      acc += hist[bin];
      if (acc >= TOPK) { cut = bin; break; }
    }
    sh_cutbits = 0x3F000000u + ((unsigned int)cut << 15);
  }
  __syncthreads();
  const unsigned int cutbits = sh_cutbits;

  for (int i = tid; i < NANCH; i += NTHR) {
    float s = src[(size_t)i * NCLS];
    if (s > 0.5f && __float_as_uint(s) >= cutbits) {
      int slot = atomicAdd(&sh_m, 1);
      if (slot < 1024)
        keys[slot] = ((unsigned long long)__float_as_uint(s) << 32) |
                     (unsigned long long)(0xFFFFFFFFu - (unsigned int)i);
    }
  }
  __syncthreads();
  int M = sh_m; if (M > 1024) M = 1024;
  for (int j = M + tid; j < 1024; j += NTHR) keys[j] = 0ull;

  for (int size = 2; size <= 1024; size <<= 1) {
    for (int st = size >> 1; st > 0; st >>= 1) {
      __syncthreads();
      for (int t = tid; t < 512; t += NTHR) {
        int lo = 2 * t - (t & (st - 1));
        int hi = lo + st;
        bool desc = ((lo & size) == 0);
        unsigned long long a = keys[lo], bb = keys[hi];
        if ((a < bb) == desc) { keys[lo] = bb; keys[hi] = a; }
      }
    }
  }
  __syncthreads();

  if (tid < TOPK) {
    unsigned long long key = keys[tid];
    int valid = (key != 0ull);
    float sc = __uint_as_float((unsigned int)(key >> 32));
    unsigned int idx = 0xFFFFFFFFu - (unsigned int)(key & 0xFFFFFFFFull);
    float4 bx = make_float4(0.f, 0.f, 0.f, 0.f);
    if (valid) bx = ((const float4*)boxes)[(size_t)b * NANCH + idx];
    sx1[tid] = bx.x; sy1[tid] = bx.y; sx2[tid] = bx.z; sy2[tid] = bx.w;
    sar[tid] = __fmul_rn(bx.z - bx.x, bx.w - bx.y);
    ssc[tid] = valid ? sc : 0.f;
    skeep[tid] = valid;
  }
  __syncthreads();

  if (tid < 64) {
    const int lane = tid;
    float x1v[4], y1v[4], x2v[4], y2v[4], av[4];
    int km = 0;
#pragma unroll
    for (int r = 0; r < 4; ++r) {
      int j = lane + (r << 6);
      if (j < TOPK) {
        x1v[r] = sx1[j]; y1v[r] = sy1[j]; x2v[r] = sx2[j]; y2v[r] = sy2[j];
        av[r] = sar[j];
        if (skeep[j]) km |= (1 << r);
      } else {
        x1v[r] = 0.f; y1v[r] = 0.f; x2v[r] = 0.f; y2v[r] = 0.f; av[r] = 0.f;
      }
    }
#pragma unroll
    for (int ri = 0; ri < 4; ++ri) {
      const int imax = (ri == 3) ? (TOPK - 192) : 64;
      for (int li = 0; li < imax; ++li) {
        const int i = (ri << 6) + li;
        int kmi = __shfl(km, li, 64);
        if (!((kmi >> ri) & 1)) continue;
        float xi1 = __shfl(x1v[ri], li, 64);
        float yi1 = __shfl(y1v[ri], li, 64);
        float xi2 = __shfl(x2v[ri], li, 64);
        float yi2 = __shfl(y2v[ri], li, 64);
        float ai  = __shfl(av[ri],  li, 64);
#pragma unroll
        for (int r = 0; r < 4; ++r) {
          int j = lane + (r << 6);
          if (j > i && j < TOPK && ((km >> r) & 1)) {
            float xx1 = fmaxf(xi1, x1v[r]);
            float yy1 = fmaxf(yi1, y1v[r]);
            float xx2 = fminf(xi2, x2v[r]);
            float yy2 = fminf(yi2, y2v[r]);
            float iw = fmaxf(0.f, __fsub_rn(xx2, xx1));
            float ih = fmaxf(0.f, __fsub_rn(yy2, yy1));
            float inter = __fmul_rn(iw, ih);
            float denom = __fsub_rn(__fadd_rn(ai, av[r]), inter);
            float iou = __fdiv_rn(inter, denom);
            if (iou > 0.5f) km &= ~(1 << r);
          }
        }
      }
    }
#pragma unroll
    for (int r = 0; r < 4; ++r) {
      int j = lane + (r << 6);
      if (j < TOPK) skeep[j] = (km >> r) & 1;
    }
  }
  __syncthreads();

  const size_t base = ((size_t)b * NCLS + c) * (TOPK * 6);
  for (int f = tid; f < TOPK * 6; f += NTHR) {
    int k = f / 6, comp = f - k * 6;
    float v = 0.f;
    if (skeep[k]) {
      switch (comp) {
        case 0: v = sx1[k]; break;
        case 1: v = sy1[k]; break;
        case 2: v = sx2[k]; break;
        case 3: v = sy2[k]; break;
        case 4: v = ssc[k]; break;
        default: v = (float)c; break;
      }
    }
    out[base + f] = v;
  }
}

// ---------------------------------------------------------------------------
extern "C" void kernel_launch(void* const* d_in, const int* in_sizes, int n_in,
                              void* d_out, int out_size, void* d_ws, size_t ws_size,
                              hipStream_t stream) {
  (void)in_sizes; (void)n_in; (void)out_size;
  const float* boxes  = (const float*)d_in[0];
  const float* scores = (const float*)d_in[1];
  float* out = (float*)d_out;

  const int NBC = B_IMG * NCLS;                                        // 640
  const size_t need_c2  = (size_t)NBC * NCHKP;                         // 174 KB
  const size_t need_cd  = (size_t)NBC * NCHK * SLOT * sizeof(uint64_t);// 33.3 MB
  const size_t need_sb  = (size_t)NBC * 256 * sizeof(float4);          // 2.6 MB
  const size_t need_sk  = (size_t)NBC * 256 * sizeof(uint64_t);        // 1.3 MB
  const size_t need_sp  = (size_t)NBC * TOPK * 4 * sizeof(uint64_t);   // 4.1 MB
  const size_t need = need_c2 + need_cd + need_sb + need_sk + need_sp; // ~41.5 MB

  if (ws_size >= need) {
    char* w = (char*)d_ws;
    unsigned char* cnt2           = (unsigned char*)w;         w += need_c2;
    unsigned long long* cand      = (unsigned long long*)w;    w += need_cd;
    float4* stagedBox             = (float4*)w;                w += need_sb;
    unsigned long long* stagedKey = (unsigned long long*)w;    w += need_sk;
    unsigned long long* supg      = (unsigned long long*)w;

    scatter_k<<<dim3(NCHK, B_IMG), NTHR, 0, stream>>>(scores, cnt2, cand);
    stage1_k<<<NBC, NTHR, 0, stream>>>(scores, boxes, cnt2, cand, stagedBox, stagedKey);
    supbuild_k<<<NBC * 4, NTHR, 0, stream>>>(stagedBox, supg);
    scanemit_k<<<NBC, NTHR, 0, stream>>>(stagedBox, stagedKey, supg, out);
  } else {
    select_nms_k<<<NBC, NTHR, 0, stream>>>(boxes, scores, out);
  }
}